// Round 11
// baseline (63.353 us; speedup 1.0000x reference)
//
#include <hip/hip_runtime.h>
#include <hip/hip_bf16.h>
#include <cstdint>

#define NROWS 8192
#define NPER  4096
#define DIM   512
#define TEMP_INV 10.0f
#define FP8_SCALE 16.0f          // z scaled by 16 before e4m3 quantization
#define DOT_UNSCALE (1.0f / 256.0f)  // undo FP8_SCALE^2 on dot products
#define NB    64        // 8192 / 128 row-blocks
#define NBLK  2080      // NB*(NB+1)/2 upper-tri 128x128 tiles
#define PAIR_OFF 32     // NPER / 128

typedef float f32x4 __attribute__((ext_vector_type(4)));

// ---------------------------------------------------------------------------
// Kernel 1: L2-normalize rows of [view0; view1] -> z (fp8 e4m3, [8192][512]),
// scaled by FP8_SCALE. Also zeroes rowsum and out.
// ---------------------------------------------------------------------------
__global__ __launch_bounds__(256) void k_normalize(const float* __restrict__ v0,
                                                   const float* __restrict__ v1,
                                                   unsigned char* __restrict__ z,
                                                   float* __restrict__ rowsum,
                                                   float* __restrict__ out) {
  if (blockIdx.x < 32) rowsum[blockIdx.x * 256 + threadIdx.x] = 0.f;
  if (blockIdx.x == 0 && threadIdx.x == 0) out[0] = 0.f;
  const int wid  = (blockIdx.x * 256 + threadIdx.x) >> 6;  // row
  const int lane = threadIdx.x & 63;
  if (wid >= NROWS) return;
  const float* src = (wid < NPER) ? (v0 + (size_t)wid * DIM)
                                  : (v1 + (size_t)(wid - NPER) * DIM);
  float4 a = *(const float4*)(src + lane * 8);
  float4 b = *(const float4*)(src + lane * 8 + 4);
  float ss = a.x*a.x + a.y*a.y + a.z*a.z + a.w*a.w
           + b.x*b.x + b.y*b.y + b.z*b.z + b.w*b.w;
  #pragma unroll
  for (int m = 1; m < 64; m <<= 1) ss += __shfl_xor(ss, m);
  float inv = FP8_SCALE / fmaxf(sqrtf(ss), 1e-12f);
  int w0 = __builtin_amdgcn_cvt_pk_fp8_f32(a.x * inv, a.y * inv, 0, false);
  w0     = __builtin_amdgcn_cvt_pk_fp8_f32(a.z * inv, a.w * inv, w0, true);
  int w1 = __builtin_amdgcn_cvt_pk_fp8_f32(b.x * inv, b.y * inv, 0, false);
  w1     = __builtin_amdgcn_cvt_pk_fp8_f32(b.z * inv, b.w * inv, w1, true);
  uint2 p; p.x = (unsigned)w0; p.y = (unsigned)w1;
  *(uint2*)(z + (size_t)wid * DIM + lane * 8) = p;
}

// ---------------------------------------------------------------------------
// Kernel 2: symmetric fused G = z z^T in FP8 e4m3. 128x128 upper-tri tiles,
// 4 waves (2x2), per-wave 64x64 (acc[4][4] = 64 AGPR), 3 blocks/CU.
// R11: lead-2 pipelined staging, BK=64, 3 slabs x (8 KB A + 8 KB B) = 48 KB
// (floor(160/48)=3 -> residency preserved), 8 windows, ONE barrier/window.
//   window k: vmcnt(4)  [S(k) done; S(k+1) in flight]
//             s_barrier [certify S(k) to all waves; also orders the stage
//                        below vs all reads of its target slab (window k-1,
//                        drained by each wave's lgkmcnt(0) pre-barrier)]
//             stage S(k+2) -> slab (k+2)%3   [k<6]
//             16 ds_read_b64 + 32 MFMA from slab k%3
//             lgkmcnt(0)
// Mechanism: R4 (bf16) proved this exact staging shape sustains 17.3 B/cyc/CU;
// fp8's 10.8 at 4 long iters is exposed drain latency. Lead-2 (~2-4k cyc)
// covers load latency + L2 queueing; 1 barrier/window halves sync cost.
// LDS rows 64 B: slot-XOR phys16Bslot = logical ^ (row&3); staging
// pre-swizzles the global source (rule #21); reads are b64, worst 4-way
// bank aliasing (~+150 cyc/window, monitor SQ_LDS_BANK_CONFLICT).
// R8 super-tile locality map kept. Pair dots harvested from bj-bi == 32.
// ---------------------------------------------------------------------------
__global__ __launch_bounds__(256, 3) void k_gemm_sym(const unsigned char* __restrict__ z,
                                                     float* __restrict__ rowsum,
                                                     float* __restrict__ s) {
  __shared__ __align__(16) unsigned char As[3][128 * 64];   // 3 x 8 KB
  __shared__ __align__(16) unsigned char Bs[3][128 * 64];   // 3 x 8 KB

  const int tid  = threadIdx.x;
  const int lane = tid & 63;
  const int w    = tid >> 6;      // 0..3
  const int wr   = w >> 1;        // 0..1 (row half)
  const int wc   = w & 1;         // 0..1 (col half)

  // T1 chunking: XCD x processes enumeration indices [x*260, (x+1)*260).
  const int orig = blockIdx.x;
  const int t = (orig & 7) * (NBLK / 8) + (orig >> 3);

  // ---- super-tile decode (R8) ----
  int a = 0;
  while (a < 7 && 484 * (a + 1) - 32 * (a + 1) * a <= t) ++a;
  int l = t - (484 * a - 32 * a * (a - 1));
  int ri, rj, sj;
  if (l < 36) {                      // diagonal super (si == sj == a)
    sj = a;
    ri = 0;
    while (l >= 8 - ri) { l -= 8 - ri; ++ri; }
    rj = ri + l;
  } else {                           // off-diagonal supers, 64 tiles each
    l -= 36;
    sj = a + 1 + (l >> 6);
    const int ll = l & 63;
    ri = ll >> 3; rj = ll & 7;
  }
  const int bi = a * 8 + ri;
  const int bj = sj * 8 + rj;
  const int brow = bi * 128;
  const int bcol = bj * 128;
  const bool diag = (bi == bj);
  const bool pair = (bj - bi == PAIR_OFF);  // contains positive-pair diagonal

  f32x4 acc[4][4];
  const f32x4 zero = {0.f, 0.f, 0.f, 0.f};
  #pragma unroll
  for (int m = 0; m < 4; ++m)
    #pragma unroll
    for (int n = 0; n < 4; ++n) acc[m][n] = zero;

  // Stage one BK=64 slab (A 8 KB + B 8 KB) into slab `slab`.
  // 4 global_load_lds per thread (2 A + 2 B). Chunk = 16 rows x 64 B = 1 KB.
  // Lane l: row R0+(l>>2); source slot pre-swizzled (l&3)^((l>>2)&3) so the
  // linear LDS write (base + lane*16) realizes phys16Bslot = logical^(row&3).
  // Global per row segment: 64 contiguous B (XOR permutes within it) = 1 line.
  const int srow3 = lane >> 2;                        // 0..15 row in chunk
  const int skof3 = 16 * ((lane & 3) ^ (srow3 & 3));  // pre-swizzled bytes
  auto stage = [&](int slab, int kt) {
    const int k0 = kt * 64;
    #pragma unroll
    for (int i = 0; i < 2; ++i) {
      const int R0 = (w * 2 + i) * 16;                // 16-row group base
      const int row_in = R0 + srow3;
      const unsigned char* ga = z + (size_t)(brow + row_in) * DIM + k0 + skof3;
      const unsigned char* gb = z + (size_t)(bcol + row_in) * DIM + k0 + skof3;
      __builtin_amdgcn_global_load_lds(
          (const __attribute__((address_space(1))) void*)ga,
          (__attribute__((address_space(3))) void*)(&As[slab][R0 * 64]), 16, 0, 0);
      __builtin_amdgcn_global_load_lds(
          (const __attribute__((address_space(1))) void*)gb,
          (__attribute__((address_space(3))) void*)(&Bs[slab][R0 * 64]), 16, 0, 0);
    }
  };

  // prologue: S0, S1 in flight (8 loads/thread)
  stage(0, 0);
  stage(1, 1);

  const int r0 = lane & 15;
  const int g  = lane >> 4;
  // per-kk byte offset of this lane's 8-B fragment within a 64-B LDS row:
  // logical 16B-slot = kk*2 + (g>>1); phys = logical ^ (r0&3); + (g&1)*8.
  int cb[2];
  #pragma unroll
  for (int kk = 0; kk < 2; ++kk)
    cb[kk] = (((kk * 2 + (g >> 1)) ^ (r0 & 3)) << 4) + ((g & 1) * 8);

  for (int kt = 0; kt < 8; ++kt) {
    const int cur = kt % 3;
    // S(kt) done; S(kt+1) stays in flight (4 loads) -- counted, never 0
    // until the last window.
    if (kt < 7) asm volatile("s_waitcnt vmcnt(4)" ::: "memory");
    else        asm volatile("s_waitcnt vmcnt(0)" ::: "memory");
    __builtin_amdgcn_s_barrier();            // single certify barrier/window
    __builtin_amdgcn_sched_barrier(0);       // pin stage after the barrier
    if (kt < 6) stage((kt + 2) % 3, kt + 2); // lead-2 prefetch

    const char* Ab = (const char*)&As[cur][0] + (size_t)(wr * 64 + r0) * 64;
    const char* Bb = (const char*)&Bs[cur][0] + (size_t)(wc * 64 + r0) * 64;
    #pragma unroll
    for (int kk = 0; kk < 2; ++kk) {
      long bfrag[4];
      #pragma unroll
      for (int n = 0; n < 4; ++n)
        bfrag[n] = *(const long*)(Bb + n * 1024 + cb[kk]);
      #pragma unroll
      for (int m = 0; m < 4; ++m) {
        long afrag = *(const long*)(Ab + m * 1024 + cb[kk]);
        #pragma unroll
        for (int n = 0; n < 4; ++n)
          acc[m][n] = __builtin_amdgcn_mfma_f32_16x16x32_fp8_fp8(
              afrag, bfrag[n], acc[m][n], 0, 0, 0);
      }
    }
    // reads of slab cur drained before the NEXT window's barrier, which
    // orders them against the stage that overwrites cur (window kt+1).
    asm volatile("s_waitcnt lgkmcnt(0)" ::: "memory");
    __builtin_amdgcn_sched_barrier(0);
  }

  // ---- epilogue: unscale; exp(10*g); row + col sums; pair dots ----
  // smem reduction arrays aliased into As slab 0 (last read at window 6;
  // all waves past barrier(7); window-7 reads use slab 1 -> disjoint bytes).
  float (*racc)[128] = (float (*)[128])As;        // [2][128]
  float (*cacc)[128] = ((float (*)[128])As) + 2;  // [2][128]

  float cs[4] = {0.f, 0.f, 0.f, 0.f};
  const int grow0 = brow + wr * 64;
  const int gcol0 = bcol + wc * 64;
  const float expc = TEMP_INV * DOT_UNSCALE;
  #pragma unroll
  for (int m = 0; m < 4; ++m) {
    #pragma unroll
    for (int j = 0; j < 4; ++j) {
      const int grow = grow0 + m * 16 + g * 4 + j;
      float v = 0.f;
      #pragma unroll
      for (int n = 0; n < 4; ++n) {
        const int gcol = gcol0 + n * 16 + r0;
        const float rawacc = acc[m][n][j];
        const float e = __expf(rawacc * expc);
        if (grow != gcol) { v += e; cs[n] += e; }   // skip self-similarity
        if (pair && (grow + NPER == gcol)) {        // positive-pair raw dot
          const float raw = rawacc * DOT_UNSCALE;
          s[grow] = raw;                            // dot(z_i, z_{i+NPER})
          s[gcol] = raw;                            // symmetric partner
        }
      }
      v += __shfl_xor(v, 1);
      v += __shfl_xor(v, 2);
      v += __shfl_xor(v, 4);
      v += __shfl_xor(v, 8);
      if (r0 == 0) racc[wc][wr * 64 + m * 16 + g * 4 + j] = v;
    }
  }
  #pragma unroll
  for (int n = 0; n < 4; ++n) {
    float v = cs[n];
    v += __shfl_xor(v, 16);
    v += __shfl_xor(v, 32);
    if (lane < 16) cacc[wr][wc * 64 + n * 16 + lane] = v;
  }
  __syncthreads();
  if (tid < 128) {
    atomicAdd(&rowsum[brow + tid], racc[0][tid] + racc[1][tid]);
  } else if (!diag) {
    const int i = tid - 128;
    atomicAdd(&rowsum[bcol + i], cacc[0][i] + cacc[1][i]);
  }
}

// ---------------------------------------------------------------------------
// Kernel 3: loss = mean_i( log(denom_i) - s_i/T ), 32 blocks + atomicAdd.
// ---------------------------------------------------------------------------
__global__ __launch_bounds__(256) void k_loss(const float* __restrict__ rowsum,
                                              const float* __restrict__ s,
                                              float* __restrict__ out) {
  __shared__ float red[4];
  const int i = blockIdx.x * 256 + threadIdx.x;
  float v = logf(rowsum[i]) - s[i] * TEMP_INV;
  #pragma unroll
  for (int m = 1; m < 64; m <<= 1) v += __shfl_xor(v, m);
  const int w = threadIdx.x >> 6;
  if ((threadIdx.x & 63) == 0) red[w] = v;
  __syncthreads();
  if (threadIdx.x == 0)
    atomicAdd(out, (red[0] + red[1] + red[2] + red[3]) * (1.0f / (float)NROWS));
}

extern "C" void kernel_launch(void* const* d_in, const int* in_sizes, int n_in,
                              void* d_out, int out_size, void* d_ws, size_t ws_size,
                              hipStream_t stream) {
  const float* v0 = (const float*)d_in[0];
  const float* v1 = (const float*)d_in[1];
  float* out = (float*)d_out;

  unsigned char* z = (unsigned char*)d_ws;                      // 8192*512 B
  float* rowsum = (float*)((char*)d_ws + (size_t)NROWS * DIM);
  float* s      = rowsum + NROWS;

  k_normalize<<<NROWS / 4, 256, 0, stream>>>(v0, v1, z, rowsum, out);
  k_gemm_sym<<<NBLK, 256, 0, stream>>>(z, rowsum, s);
  k_loss<<<NROWS / 256, 256, 0, stream>>>(rowsum, s, out);
}

// Round 12
// 49.149 us; speedup vs baseline: 1.2890x; 1.2890x over previous
//
#include <hip/hip_runtime.h>
#include <hip/hip_bf16.h>
#include <cstdint>

#define NROWS 8192
#define NPER  4096
#define DIM   512
#define TEMP_INV 10.0f
#define FP8_SCALE 16.0f          // z scaled by 16 before e4m3 quantization
#define DOT_UNSCALE (1.0f / 256.0f)  // undo FP8_SCALE^2 on dot products
#define NB    64        // 8192 / 128 row-blocks
#define NBLK  2080      // NB*(NB+1)/2 upper-tri 128x128 tiles
#define PAIR_OFF 32     // NPER / 128

typedef float f32x4 __attribute__((ext_vector_type(4)));
typedef long  lx2   __attribute__((ext_vector_type(2)));   // 16 B = 2 fp8 frags

// ---------------------------------------------------------------------------
// Kernel 1: L2-normalize rows of [view0; view1] -> z (fp8 e4m3, [8192][512]),
// scaled by FP8_SCALE (moves typical |z|~0.04 out of the subnormal zone;
// e4m3 max 448 >> 16). Also zeroes rowsum and out.
// ---------------------------------------------------------------------------
__global__ __launch_bounds__(256) void k_normalize(const float* __restrict__ v0,
                                                   const float* __restrict__ v1,
                                                   unsigned char* __restrict__ z,
                                                   float* __restrict__ rowsum,
                                                   float* __restrict__ out) {
  if (blockIdx.x < 32) rowsum[blockIdx.x * 256 + threadIdx.x] = 0.f;
  if (blockIdx.x == 0 && threadIdx.x == 0) out[0] = 0.f;
  const int wid  = (blockIdx.x * 256 + threadIdx.x) >> 6;  // row
  const int lane = threadIdx.x & 63;
  if (wid >= NROWS) return;
  const float* src = (wid < NPER) ? (v0 + (size_t)wid * DIM)
                                  : (v1 + (size_t)(wid - NPER) * DIM);
  float4 a = *(const float4*)(src + lane * 8);
  float4 b = *(const float4*)(src + lane * 8 + 4);
  float ss = a.x*a.x + a.y*a.y + a.z*a.z + a.w*a.w
           + b.x*b.x + b.y*b.y + b.z*b.z + b.w*b.w;
  #pragma unroll
  for (int m = 1; m < 64; m <<= 1) ss += __shfl_xor(ss, m);
  float inv = FP8_SCALE / fmaxf(sqrtf(ss), 1e-12f);
  // pack 8 fp8 e4m3 (hardware v_cvt_pk_fp8_f32, RNE, OCP format on gfx950)
  int w0 = __builtin_amdgcn_cvt_pk_fp8_f32(a.x * inv, a.y * inv, 0, false);
  w0     = __builtin_amdgcn_cvt_pk_fp8_f32(a.z * inv, a.w * inv, w0, true);
  int w1 = __builtin_amdgcn_cvt_pk_fp8_f32(b.x * inv, b.y * inv, 0, false);
  w1     = __builtin_amdgcn_cvt_pk_fp8_f32(b.z * inv, b.w * inv, w1, true);
  uint2 p; p.x = (unsigned)w0; p.y = (unsigned)w1;
  *(uint2*)(z + (size_t)wid * DIM + lane * 8) = p;
}

// ---------------------------------------------------------------------------
// Kernel 2: symmetric fused G = z z^T in FP8 e4m3 (mfma_f32_16x16x32_fp8_fp8,
// bf16-rate, half the bytes). 128x128 upper-tri tiles, 4 waves (2x2),
// per-wave 64x64 (acc[4][4] = 64 AGPR), BK=128 SINGLE-buffered (32 KB LDS).
// R12: this is the R10-verified kernel (GEMM ~40.3 us, 0 bank conflicts)
// with __launch_bounds__(256, 4): at 56 VGPR + 64 AGPR = 120 regs/wave
// (8 under the 128-reg 4-waves/SIMD boundary where R5's bf16 attempt was
// denied) and 4 x 32 KB = 128 KB LDS, a 4th independent block/CU is
// resource-feasible. TLP from independent blocks is the only lever that
// has worked on this kernel (1->2->3 blocks: 70->67->51 us); the per-window
// vmcnt(0) drain is the exposed cost it hides.
// Conflict-free LDS reads: 16 B per lane (ds_read_b128) at phys 16B-slot
// (2g+p)^(r0&7), row stride 128 B -- the R4/R10-verified 0-conflict pattern.
// Each b128 holds TWO 8-B MFMA fragments; k-regrouping is applied
// identically to A and B so the dot product is unchanged.
// Staging pre-swizzles the global source (rule #21). R8 super-tile locality
// map kept. Positive-pair dots harvested from tiles with bj-bi == 32.
// ---------------------------------------------------------------------------
__global__ __launch_bounds__(256, 4) void k_gemm_sym(const unsigned char* __restrict__ z,
                                                     float* __restrict__ rowsum,
                                                     float* __restrict__ s) {
  __shared__ __align__(16) unsigned char As[128 * 128];   // 16 KB
  __shared__ __align__(16) unsigned char Bs[128 * 128];   // 16 KB

  const int tid  = threadIdx.x;
  const int lane = tid & 63;
  const int w    = tid >> 6;      // 0..3
  const int wr   = w >> 1;        // 0..1 (row half)
  const int wc   = w & 1;         // 0..1 (col half)

  // T1 chunking: XCD x processes enumeration indices [x*260, (x+1)*260).
  const int orig = blockIdx.x;
  const int t = (orig & 7) * (NBLK / 8) + (orig >> 3);

  // ---- super-tile decode (R8) ----
  int a = 0;
  while (a < 7 && 484 * (a + 1) - 32 * (a + 1) * a <= t) ++a;
  int l = t - (484 * a - 32 * a * (a - 1));
  int ri, rj, sj;
  if (l < 36) {                      // diagonal super (si == sj == a)
    sj = a;
    ri = 0;
    while (l >= 8 - ri) { l -= 8 - ri; ++ri; }
    rj = ri + l;
  } else {                           // off-diagonal supers, 64 tiles each
    l -= 36;
    sj = a + 1 + (l >> 6);
    const int ll = l & 63;
    ri = ll >> 3; rj = ll & 7;
  }
  const int bi = a * 8 + ri;
  const int bj = sj * 8 + rj;
  const int brow = bi * 128;
  const int bcol = bj * 128;
  const bool diag = (bi == bj);
  const bool pair = (bj - bi == PAIR_OFF);  // contains positive-pair diagonal

  f32x4 acc[4][4];
  const f32x4 zero = {0.f, 0.f, 0.f, 0.f};
  #pragma unroll
  for (int m = 0; m < 4; ++m)
    #pragma unroll
    for (int n = 0; n < 4; ++n) acc[m][n] = zero;

  // stage one BK=128 K-slab (A and B tiles, 16 KB each). 8 global_load_lds
  // per thread (4 A + 4 B). Chunk = 8 rows x 128 B = 1 KB (one wave-load).
  // LDS dest linear; global source pre-swizzled: 16B-slot ^= (row & 7).
  const int srow = (lane >> 3);                  // 0..7 row within chunk
  const int skof = 16 * ((lane & 7) ^ srow);     // pre-swizzled k-offset (bytes)
  auto stage = [&](int k0) {
    #pragma unroll
    for (int i = 0; i < 4; ++i) {
      const int c = w * 4 + i;                   // chunk 0..15 (8 rows each)
      const int row_in = c * 8 + srow;
      const unsigned char* ga = z + (size_t)(brow + row_in) * DIM + k0 + skof;
      const unsigned char* gb = z + (size_t)(bcol + row_in) * DIM + k0 + skof;
      __builtin_amdgcn_global_load_lds(
          (const __attribute__((address_space(1))) void*)ga,
          (__attribute__((address_space(3))) void*)(&As[c * 1024]), 16, 0, 0);
      __builtin_amdgcn_global_load_lds(
          (const __attribute__((address_space(1))) void*)gb,
          (__attribute__((address_space(3))) void*)(&Bs[c * 1024]), 16, 0, 0);
    }
  };

  const int r0 = lane & 15;
  const int g  = lane >> 4;

  for (int kt = 0; kt < 4; ++kt) {
    stage(kt * 128);
    // single buffer: own loads drained, then all waves' loads visible.
    asm volatile("s_waitcnt vmcnt(0)" ::: "memory");
    __builtin_amdgcn_s_barrier();

    const char* Ab = (const char*)&As[0] + (size_t)(wr * 64 + r0) * 128;
    const char* Bb = (const char*)&Bs[0] + (size_t)(wc * 64 + r0) * 128;
    #pragma unroll
    for (int p = 0; p < 2; ++p) {
      // 16-B read at phys slot (2g+p)^(r0&7): R4-verified 0-conflict pattern.
      const int cb = (((2 * g + p) ^ (r0 & 7)) << 4);
      lx2 bfrag[4];
      #pragma unroll
      for (int n = 0; n < 4; ++n)
        bfrag[n] = *(const lx2*)(Bb + n * (16 * 128) + cb);
      #pragma unroll
      for (int m = 0; m < 4; ++m) {
        lx2 afrag = *(const lx2*)(Ab + m * (16 * 128) + cb);
        #pragma unroll
        for (int n = 0; n < 4; ++n) {
          acc[m][n] = __builtin_amdgcn_mfma_f32_16x16x32_fp8_fp8(
              afrag[0], bfrag[n][0], acc[m][n], 0, 0, 0);
          acc[m][n] = __builtin_amdgcn_mfma_f32_16x16x32_fp8_fp8(
              afrag[1], bfrag[n][1], acc[m][n], 0, 0, 0);
        }
      }
    }
    // all LDS reads done in this wave, sync all waves -> safe to overwrite.
    asm volatile("s_waitcnt lgkmcnt(0)" ::: "memory");
    __builtin_amdgcn_sched_barrier(0);
    __builtin_amdgcn_s_barrier();
  }

  // ---- epilogue: unscale; exp(10*g); row + col sums; pair dots ----
  // smem reduction arrays aliased into As (all LDS reads drained above).
  float (*racc)[128] = (float (*)[128])As;        // [2][128]
  float (*cacc)[128] = ((float (*)[128])As) + 2;  // [2][128]

  float cs[4] = {0.f, 0.f, 0.f, 0.f};
  const int grow0 = brow + wr * 64;
  const int gcol0 = bcol + wc * 64;
  const float expc = TEMP_INV * DOT_UNSCALE;
  #pragma unroll
  for (int m = 0; m < 4; ++m) {
    #pragma unroll
    for (int j = 0; j < 4; ++j) {
      const int grow = grow0 + m * 16 + g * 4 + j;
      float v = 0.f;
      #pragma unroll
      for (int n = 0; n < 4; ++n) {
        const int gcol = gcol0 + n * 16 + r0;
        const float rawacc = acc[m][n][j];
        const float e = __expf(rawacc * expc);
        if (grow != gcol) { v += e; cs[n] += e; }   // skip self-similarity
        if (pair && (grow + NPER == gcol)) {        // positive-pair raw dot
          const float raw = rawacc * DOT_UNSCALE;
          s[grow] = raw;                            // dot(z_i, z_{i+NPER})
          s[gcol] = raw;                            // symmetric partner
        }
      }
      v += __shfl_xor(v, 1);
      v += __shfl_xor(v, 2);
      v += __shfl_xor(v, 4);
      v += __shfl_xor(v, 8);
      if (r0 == 0) racc[wc][wr * 64 + m * 16 + g * 4 + j] = v;
    }
  }
  #pragma unroll
  for (int n = 0; n < 4; ++n) {
    float v = cs[n];
    v += __shfl_xor(v, 16);
    v += __shfl_xor(v, 32);
    if (lane < 16) cacc[wr][wc * 64 + n * 16 + lane] = v;
  }
  __syncthreads();
  if (tid < 128) {
    atomicAdd(&rowsum[brow + tid], racc[0][tid] + racc[1][tid]);
  } else if (!diag) {
    const int i = tid - 128;
    atomicAdd(&rowsum[bcol + i], cacc[0][i] + cacc[1][i]);
  }
}

// ---------------------------------------------------------------------------
// Kernel 3: loss = mean_i( log(denom_i) - s_i/T ), 32 blocks + atomicAdd
// (out zeroed in k_normalize; stream order guarantees visibility).
// ---------------------------------------------------------------------------
__global__ __launch_bounds__(256) void k_loss(const float* __restrict__ rowsum,
                                              const float* __restrict__ s,
                                              float* __restrict__ out) {
  __shared__ float red[4];
  const int i = blockIdx.x * 256 + threadIdx.x;
  float v = logf(rowsum[i]) - s[i] * TEMP_INV;
  #pragma unroll
  for (int m = 1; m < 64; m <<= 1) v += __shfl_xor(v, m);
  const int w = threadIdx.x >> 6;
  if ((threadIdx.x & 63) == 0) red[w] = v;
  __syncthreads();
  if (threadIdx.x == 0)
    atomicAdd(out, (red[0] + red[1] + red[2] + red[3]) * (1.0f / (float)NROWS));
}

extern "C" void kernel_launch(void* const* d_in, const int* in_sizes, int n_in,
                              void* d_out, int out_size, void* d_ws, size_t ws_size,
                              hipStream_t stream) {
  const float* v0 = (const float*)d_in[0];
  const float* v1 = (const float*)d_in[1];
  float* out = (float*)d_out;

  unsigned char* z = (unsigned char*)d_ws;                      // 8192*512 B
  float* rowsum = (float*)((char*)d_ws + (size_t)NROWS * DIM);
  float* s      = rowsum + NROWS;

  k_normalize<<<NROWS / 4, 256, 0, stream>>>(v0, v1, z, rowsum, out);
  k_gemm_sym<<<NBLK, 256, 0, stream>>>(z, rowsum, s);
  k_loss<<<NROWS / 256, 256, 0, stream>>>(rowsum, s, out);
}